// Round 1
// baseline (9602.111 us; speedup 1.0000x reference)
//
#include <hip/hip_runtime.h>

#define MNODES 50000
#define NEDGES 800000
#define DIN    128
#define DD     256
#define D2     512
#define NLAYERS 3
#define BN_EPS 1e-5f

// ---------------- elementwise ----------------
__global__ void k_copy(const float* __restrict__ src, float* __restrict__ dst, int n4) {
    int i = blockIdx.x * blockDim.x + threadIdx.x;
    if (i < n4) ((float4*)dst)[i] = ((const float4*)src)[i];
}

__global__ void k_zero(float* p, int n) {
    int i = blockIdx.x * blockDim.x + threadIdx.x;
    if (i < n) p[i] = 0.f;
}

// scatter-add: one wave (64 lanes) per edge, lane handles 4 consecutive feats
__global__ void k_scatter(const int* __restrict__ ei, const float* __restrict__ x,
                          float* __restrict__ agg) {
    int eid  = blockIdx.x * 4 + (threadIdx.x >> 6);
    int lane = threadIdx.x & 63;
    if (eid >= NEDGES) return;
    int src = ei[eid * 2];
    int dst = ei[eid * 2 + 1];
    float4 v = ((const float4*)(x + (size_t)src * DD))[lane];
    float* d = agg + (size_t)dst * DD + lane * 4;
    atomicAdd(d + 0, v.x);
    atomicAdd(d + 1, v.y);
    atomicAdd(d + 2, v.z);
    atomicAdd(d + 3, v.w);
}

// column sums / sumsq for BN. block=256 threads; each thread owns col tid (+256)
template<int NC>
__global__ void k_colstats(const float* __restrict__ h, float* __restrict__ sums,
                           float* __restrict__ sumsq) {
    int tid = threadIdx.x;
    float s0 = 0.f, q0 = 0.f, s1 = 0.f, q1 = 0.f;
    for (int row = blockIdx.x; row < MNODES; row += gridDim.x) {
        const float* r = h + (size_t)row * NC;
        float v0 = r[tid];
        s0 += v0; q0 += v0 * v0;
        if (NC == 512) {
            float v1 = r[tid + 256];
            s1 += v1; q1 += v1 * v1;
        }
    }
    atomicAdd(&sums[tid], s0);
    atomicAdd(&sumsq[tid], q0);
    if (NC == 512) {
        atomicAdd(&sums[tid + 256], s1);
        atomicAdd(&sumsq[tid + 256], q1);
    }
}

// per-column affine coefficients: y = ca*x + cc  == gamma*(x-mean)*rsqrt(var+eps)+beta
__global__ void k_coeffs(const float* __restrict__ sums, const float* __restrict__ sumsq,
                         const float* __restrict__ g, const float* __restrict__ beta,
                         float* __restrict__ ca, float* __restrict__ cc, int n) {
    int c = blockIdx.x * blockDim.x + threadIdx.x;
    if (c >= n) return;
    float mean = sums[c] * (1.0f / MNODES);
    float var  = sumsq[c] * (1.0f / MNODES) - mean * mean;
    float a    = g[c] * rsqrtf(var + BN_EPS);
    ca[c] = a;
    cc[c] = beta[c] - a * mean;
}

// out = ca[col]*h + cc[col]   (NC must be power of 2)
template<int NC>
__global__ void k_apply(const float* __restrict__ h, const float* __restrict__ ca,
                        const float* __restrict__ cc, float* __restrict__ out, int n4) {
    int i = blockIdx.x * blockDim.x + threadIdx.x;
    if (i >= n4) return;
    int c = (i * 4) & (NC - 1);
    float4 v = ((const float4*)h)[i];
    v.x = ca[c + 0] * v.x + cc[c + 0];
    v.y = ca[c + 1] * v.y + cc[c + 1];
    v.z = ca[c + 2] * v.z + cc[c + 2];
    v.w = ca[c + 3] * v.w + cc[c + 3];
    ((float4*)out)[i] = v;
}

// ---------------- tiled fp32 GEMM ----------------
// out[M,N] = op(A)[M,K] @ W[K,N] + bias[N]  (+ resid[M,N])
// PRE: element transform on A at staging: a = relu(pa[k]*a + pc[k])
// 64x64 tile, BK=32, 256 threads, 4x4 micro-tile per thread.
template<int PRE, int RES>
__global__ __launch_bounds__(256)
void k_gemm(const float* __restrict__ A, const float* __restrict__ W,
            const float* __restrict__ bias, const float* __restrict__ resid,
            const float* __restrict__ pa, const float* __restrict__ pc,
            float* __restrict__ out, int M, int K, int N) {
    __shared__ float As[32][68];   // [k][m], +4 pad keeps 16B alignment
    __shared__ float Bs[32][68];   // [k][n]
    int tid = threadIdx.x;
    int tx = tid & 15, ty = tid >> 4;
    int m0 = blockIdx.y * 64, n0 = blockIdx.x * 64;
    float acc[4][4] = {};

    for (int kt = 0; kt < K; kt += 32) {
        // stage A tile (64 rows x 32 k), transposed into As[k][m]
        #pragma unroll
        for (int i = 0; i < 2; i++) {
            int t = tid + i * 256;
            int row = t >> 3;
            int k4  = (t & 7) * 4;
            int grow = m0 + row;
            float4 f = make_float4(0.f, 0.f, 0.f, 0.f);
            if (grow < M) f = *(const float4*)(A + (size_t)grow * K + kt + k4);
            if (PRE) {
                int c = kt + k4;
                f.x = fmaxf(pa[c + 0] * f.x + pc[c + 0], 0.f);
                f.y = fmaxf(pa[c + 1] * f.y + pc[c + 1], 0.f);
                f.z = fmaxf(pa[c + 2] * f.z + pc[c + 2], 0.f);
                f.w = fmaxf(pa[c + 3] * f.w + pc[c + 3], 0.f);
            }
            As[k4 + 0][row] = f.x;
            As[k4 + 1][row] = f.y;
            As[k4 + 2][row] = f.z;
            As[k4 + 3][row] = f.w;
        }
        // stage B tile (32 k x 64 n)
        #pragma unroll
        for (int i = 0; i < 2; i++) {
            int t = tid + i * 256;
            int kk = t >> 4;
            int n4 = (t & 15) * 4;
            *(float4*)&Bs[kk][n4] = *(const float4*)(W + (size_t)(kt + kk) * N + n0 + n4);
        }
        __syncthreads();
        #pragma unroll
        for (int k = 0; k < 32; k++) {
            float4 a = *(float4*)&As[k][ty * 4];
            float4 b = *(float4*)&Bs[k][tx * 4];
            float av[4] = {a.x, a.y, a.z, a.w};
            float bv[4] = {b.x, b.y, b.z, b.w};
            #pragma unroll
            for (int i = 0; i < 4; i++)
                #pragma unroll
                for (int j = 0; j < 4; j++)
                    acc[i][j] = fmaf(av[i], bv[j], acc[i][j]);
        }
        __syncthreads();
    }

    // epilogue
    #pragma unroll
    for (int i = 0; i < 4; i++) {
        int row = m0 + ty * 4 + i;
        if (row >= M) break;
        int col = n0 + tx * 4;
        float4 o;
        o.x = acc[i][0] + bias[col + 0];
        o.y = acc[i][1] + bias[col + 1];
        o.z = acc[i][2] + bias[col + 2];
        o.w = acc[i][3] + bias[col + 3];
        if (RES) {
            float4 r = *(const float4*)(resid + (size_t)row * N + col);
            o.x += r.x; o.y += r.y; o.z += r.z; o.w += r.w;
        }
        *(float4*)(out + (size_t)row * N + col) = o;
    }
}

extern "C" void kernel_launch(void* const* d_in, const int* in_sizes, int n_in,
                              void* d_out, int out_size, void* d_ws, size_t ws_size,
                              hipStream_t stream) {
    const float* pre   = (const float*)d_in[0];
    const int*   ei    = (const int*)d_in[1];
    const float* W0    = (const float*)d_in[2];
    const float* b0    = (const float*)d_in[3];
    const float* W1    = (const float*)d_in[4];
    const float* b1    = (const float*)d_in[5];
    const float* g1    = (const float*)d_in[6];
    const float* beta1 = (const float*)d_in[7];
    const float* W2    = (const float*)d_in[8];
    const float* b2    = (const float*)d_in[9];
    const float* gf    = (const float*)d_in[10];
    const float* betaf = (const float*)d_in[11];

    float* X = (float*)d_out;              // x lives in d_out (fully rewritten)
    float* ws = (float*)d_ws;
    float* HIN   = ws;                           // M*256 (reused as layer-2 output)
    float* H1    = HIN + (size_t)MNODES * DD;    // M*512
    float* sums  = H1 + (size_t)MNODES * D2;     // 512
    float* sumsq = sums + D2;                    // 512
    float* ca    = sumsq + D2;                   // 512
    float* cc    = ca + D2;                      // 512

    dim3 blk(256);
    int mt = (MNODES + 63) / 64;
    int nelem4 = MNODES * DD / 4;

    // X = pre @ W0 + b0
    k_gemm<0, 0><<<dim3(DD / 64, mt), blk, 0, stream>>>(
        pre, W0, b0, nullptr, nullptr, nullptr, X, MNODES, DIN, DD);

    for (int l = 0; l < NLAYERS; l++) {
        // HIN = X; HIN[dst] += X[src]
        k_copy<<<(nelem4 + 255) / 256, blk, 0, stream>>>(X, HIN, nelem4);
        k_scatter<<<(NEDGES + 3) / 4, blk, 0, stream>>>(ei, X, HIN);

        // H1 = HIN @ W1[l] + b1[l]
        k_gemm<0, 0><<<dim3(D2 / 64, mt), blk, 0, stream>>>(
            HIN, W1 + (size_t)l * DD * D2, b1 + (size_t)l * D2,
            nullptr, nullptr, nullptr, H1, MNODES, DD, D2);

        // BN coeffs for H1 (512 cols)
        k_zero<<<(2 * D2 + 255) / 256, blk, 0, stream>>>(sums, 2 * D2);
        k_colstats<512><<<1024, blk, 0, stream>>>(H1, sums, sumsq);
        k_coeffs<<<2, blk, 0, stream>>>(sums, sumsq, g1 + (size_t)l * D2,
                                        beta1 + (size_t)l * D2, ca, cc, D2);

        // HIN = relu(bn(H1)) @ W2[l] + b2[l] + X
        k_gemm<1, 1><<<dim3(DD / 64, mt), blk, 0, stream>>>(
            H1, W2 + (size_t)l * D2 * DD, b2 + (size_t)l * DD,
            X, ca, cc, HIN, MNODES, D2, DD);

        // BN coeffs for HIN (256 cols)
        k_zero<<<(2 * D2 + 255) / 256, blk, 0, stream>>>(sums, 2 * D2);
        k_colstats<256><<<1024, blk, 0, stream>>>(HIN, sums, sumsq);
        k_coeffs<<<1, blk, 0, stream>>>(sums, sumsq, gf + (size_t)l * DD,
                                        betaf + (size_t)l * DD, ca, cc, DD);

        // X = bn(HIN)  (last layer: X is d_out, so this writes the output)
        k_apply<256><<<(nelem4 + 255) / 256, blk, 0, stream>>>(HIN, ca, cc, X, nelem4);
    }
}

// Round 2
// 2049.042 us; speedup vs baseline: 4.6861x; 4.6861x over previous
//
#include <hip/hip_runtime.h>

#define MNODES 50000
#define NEDGES 800000
#define DIN    128
#define DD     256
#define D2     512
#define NLAYERS 3
#define BN_EPS 1e-5f

// ---------------- CSR build (once per launch) ----------------
__global__ void k_zero_int(int* p, int n) {
    int i = blockIdx.x * blockDim.x + threadIdx.x;
    if (i < n) p[i] = 0;
}

__global__ void k_hist(const int* __restrict__ ei, int* __restrict__ deg) {
    int e = blockIdx.x * blockDim.x + threadIdx.x;
    if (e < NEDGES) atomicAdd(&deg[ei[e * 2 + 1]], 1);
}

// single-block (1024 threads) exclusive scan: rowptr[0..n], cursor[i]=excl
__global__ __launch_bounds__(1024)
void k_scan(const int* __restrict__ deg, int* __restrict__ rowptr,
            int* __restrict__ cursor, int n) {
    __shared__ int tmp[1024];
    __shared__ int carry;
    int tid = threadIdx.x;
    if (tid == 0) { carry = 0; rowptr[0] = 0; }
    __syncthreads();
    for (int base = 0; base < n; base += 1024) {
        int i = base + tid;
        int v = (i < n) ? deg[i] : 0;
        tmp[tid] = v;
        __syncthreads();
        #pragma unroll
        for (int off = 1; off < 1024; off <<= 1) {
            int t = (tid >= off) ? tmp[tid - off] : 0;
            __syncthreads();
            tmp[tid] += t;
            __syncthreads();
        }
        if (i < n) {
            int incl = tmp[tid] + carry;
            rowptr[i + 1] = incl;
            cursor[i] = incl - v;
        }
        __syncthreads();
        if (tid == 0) carry += tmp[1023];
        __syncthreads();
    }
}

__global__ void k_fill(const int* __restrict__ ei, int* __restrict__ cursor,
                       int* __restrict__ col) {
    int e = blockIdx.x * blockDim.x + threadIdx.x;
    if (e < NEDGES) {
        int pos = atomicAdd(&cursor[ei[e * 2 + 1]], 1);
        col[pos] = ei[e * 2];
    }
}

// ---------------- gather aggregation: h[n] = x[n] + sum_{s in in(n)} x[s] ----
// one wave per node; lane handles float4 at offset lane (256 floats = 64 f4)
__global__ void k_gather(const int* __restrict__ rowptr, const int* __restrict__ col,
                         const float* __restrict__ x, float* __restrict__ h) {
    int node = blockIdx.x * 4 + (threadIdx.x >> 6);
    int lane = threadIdx.x & 63;
    if (node >= MNODES) return;
    float4 acc = ((const float4*)(x + (size_t)node * DD))[lane];
    int s = rowptr[node], e = rowptr[node + 1];
    int i = s;
    for (; i + 1 < e; i += 2) {  // 2-way unroll for load overlap
        int s0 = col[i], s1 = col[i + 1];
        float4 v0 = ((const float4*)(x + (size_t)s0 * DD))[lane];
        float4 v1 = ((const float4*)(x + (size_t)s1 * DD))[lane];
        acc.x += v0.x + v1.x; acc.y += v0.y + v1.y;
        acc.z += v0.z + v1.z; acc.w += v0.w + v1.w;
    }
    if (i < e) {
        float4 v = ((const float4*)(x + (size_t)col[i] * DD))[lane];
        acc.x += v.x; acc.y += v.y; acc.z += v.z; acc.w += v.w;
    }
    ((float4*)(h + (size_t)node * DD))[lane] = acc;
}

// ---------------- BN stats ----------------
__global__ void k_zero(float* p, int n) {
    int i = blockIdx.x * blockDim.x + threadIdx.x;
    if (i < n) p[i] = 0.f;
}

template<int NC>
__global__ void k_colstats(const float* __restrict__ h, float* __restrict__ sums,
                           float* __restrict__ sumsq) {
    int tid = threadIdx.x;
    float s0 = 0.f, q0 = 0.f, s1 = 0.f, q1 = 0.f;
    for (int row = blockIdx.x; row < MNODES; row += gridDim.x) {
        const float* r = h + (size_t)row * NC;
        float v0 = r[tid];
        s0 += v0; q0 += v0 * v0;
        if (NC == 512) {
            float v1 = r[tid + 256];
            s1 += v1; q1 += v1 * v1;
        }
    }
    atomicAdd(&sums[tid], s0);
    atomicAdd(&sumsq[tid], q0);
    if (NC == 512) {
        atomicAdd(&sums[tid + 256], s1);
        atomicAdd(&sumsq[tid + 256], q1);
    }
}

__global__ void k_coeffs(const float* __restrict__ sums, const float* __restrict__ sumsq,
                         const float* __restrict__ g, const float* __restrict__ beta,
                         float* __restrict__ ca, float* __restrict__ cc, int n) {
    int c = blockIdx.x * blockDim.x + threadIdx.x;
    if (c >= n) return;
    float mean = sums[c] * (1.0f / MNODES);
    float var  = sumsq[c] * (1.0f / MNODES) - mean * mean;
    float a    = g[c] * rsqrtf(var + BN_EPS);
    ca[c] = a;
    cc[c] = beta[c] - a * mean;
}

template<int NC>
__global__ void k_apply(const float* __restrict__ h, const float* __restrict__ ca,
                        const float* __restrict__ cc, float* __restrict__ out, int n4) {
    int i = blockIdx.x * blockDim.x + threadIdx.x;
    if (i >= n4) return;
    int c = (i * 4) & (NC - 1);
    float4 v = ((const float4*)h)[i];
    v.x = ca[c + 0] * v.x + cc[c + 0];
    v.y = ca[c + 1] * v.y + cc[c + 1];
    v.z = ca[c + 2] * v.z + cc[c + 2];
    v.w = ca[c + 3] * v.w + cc[c + 3];
    ((float4*)out)[i] = v;
}

// ---------------- tiled fp32 GEMM ----------------
template<int PRE, int RES>
__global__ __launch_bounds__(256)
void k_gemm(const float* __restrict__ A, const float* __restrict__ W,
            const float* __restrict__ bias, const float* __restrict__ resid,
            const float* __restrict__ pa, const float* __restrict__ pc,
            float* __restrict__ out, int M, int K, int N) {
    __shared__ float As[32][68];
    __shared__ float Bs[32][68];
    int tid = threadIdx.x;
    int tx = tid & 15, ty = tid >> 4;
    int m0 = blockIdx.y * 64, n0 = blockIdx.x * 64;
    float acc[4][4] = {};

    for (int kt = 0; kt < K; kt += 32) {
        #pragma unroll
        for (int i = 0; i < 2; i++) {
            int t = tid + i * 256;
            int row = t >> 3;
            int k4  = (t & 7) * 4;
            int grow = m0 + row;
            float4 f = make_float4(0.f, 0.f, 0.f, 0.f);
            if (grow < M) f = *(const float4*)(A + (size_t)grow * K + kt + k4);
            if (PRE) {
                int c = kt + k4;
                f.x = fmaxf(pa[c + 0] * f.x + pc[c + 0], 0.f);
                f.y = fmaxf(pa[c + 1] * f.y + pc[c + 1], 0.f);
                f.z = fmaxf(pa[c + 2] * f.z + pc[c + 2], 0.f);
                f.w = fmaxf(pa[c + 3] * f.w + pc[c + 3], 0.f);
            }
            As[k4 + 0][row] = f.x;
            As[k4 + 1][row] = f.y;
            As[k4 + 2][row] = f.z;
            As[k4 + 3][row] = f.w;
        }
        #pragma unroll
        for (int i = 0; i < 2; i++) {
            int t = tid + i * 256;
            int kk = t >> 4;
            int n4 = (t & 15) * 4;
            *(float4*)&Bs[kk][n4] = *(const float4*)(W + (size_t)(kt + kk) * N + n0 + n4);
        }
        __syncthreads();
        #pragma unroll
        for (int k = 0; k < 32; k++) {
            float4 a = *(float4*)&As[k][ty * 4];
            float4 b = *(float4*)&Bs[k][tx * 4];
            float av[4] = {a.x, a.y, a.z, a.w};
            float bv[4] = {b.x, b.y, b.z, b.w};
            #pragma unroll
            for (int i = 0; i < 4; i++)
                #pragma unroll
                for (int j = 0; j < 4; j++)
                    acc[i][j] = fmaf(av[i], bv[j], acc[i][j]);
        }
        __syncthreads();
    }

    #pragma unroll
    for (int i = 0; i < 4; i++) {
        int row = m0 + ty * 4 + i;
        if (row >= M) break;
        int col = n0 + tx * 4;
        float4 o;
        o.x = acc[i][0] + bias[col + 0];
        o.y = acc[i][1] + bias[col + 1];
        o.z = acc[i][2] + bias[col + 2];
        o.w = acc[i][3] + bias[col + 3];
        if (RES) {
            float4 r = *(const float4*)(resid + (size_t)row * N + col);
            o.x += r.x; o.y += r.y; o.z += r.z; o.w += r.w;
        }
        *(float4*)(out + (size_t)row * N + col) = o;
    }
}

extern "C" void kernel_launch(void* const* d_in, const int* in_sizes, int n_in,
                              void* d_out, int out_size, void* d_ws, size_t ws_size,
                              hipStream_t stream) {
    const float* pre   = (const float*)d_in[0];
    const int*   ei    = (const int*)d_in[1];
    const float* W0    = (const float*)d_in[2];
    const float* b0    = (const float*)d_in[3];
    const float* W1    = (const float*)d_in[4];
    const float* b1    = (const float*)d_in[5];
    const float* g1    = (const float*)d_in[6];
    const float* beta1 = (const float*)d_in[7];
    const float* W2    = (const float*)d_in[8];
    const float* b2    = (const float*)d_in[9];
    const float* gf    = (const float*)d_in[10];
    const float* betaf = (const float*)d_in[11];

    float* X = (float*)d_out;
    float* ws = (float*)d_ws;
    float* HIN   = ws;                           // M*256
    float* H1    = HIN + (size_t)MNODES * DD;    // M*512
    float* sums  = H1 + (size_t)MNODES * D2;     // 512
    float* sumsq = sums + D2;                    // 512
    float* ca    = sumsq + D2;                   // 512
    float* cc    = ca + D2;                      // 512
    int*   deg    = (int*)(cc + D2);             // N
    int*   rowptr = deg + MNODES;                // N+1
    int*   cursor = rowptr + MNODES + 1;         // N
    int*   col    = cursor + MNODES;             // E

    dim3 blk(256);
    int mt = (MNODES + 63) / 64;
    int nelem4 = MNODES * DD / 4;

    // ---- build CSR (dst -> srcs) once ----
    k_zero_int<<<(MNODES + 255) / 256, blk, 0, stream>>>(deg, MNODES);
    k_hist<<<(NEDGES + 255) / 256, blk, 0, stream>>>(ei, deg);
    k_scan<<<1, 1024, 0, stream>>>(deg, rowptr, cursor, MNODES);
    k_fill<<<(NEDGES + 255) / 256, blk, 0, stream>>>(ei, cursor, col);

    // X = pre @ W0 + b0
    k_gemm<0, 0><<<dim3(DD / 64, mt), blk, 0, stream>>>(
        pre, W0, b0, nullptr, nullptr, nullptr, X, MNODES, DIN, DD);

    for (int l = 0; l < NLAYERS; l++) {
        // HIN = X + gather(X)
        k_gather<<<(MNODES + 3) / 4, blk, 0, stream>>>(rowptr, col, X, HIN);

        // H1 = HIN @ W1[l] + b1[l]
        k_gemm<0, 0><<<dim3(D2 / 64, mt), blk, 0, stream>>>(
            HIN, W1 + (size_t)l * DD * D2, b1 + (size_t)l * D2,
            nullptr, nullptr, nullptr, H1, MNODES, DD, D2);

        // BN coeffs for H1 (512 cols)
        k_zero<<<(2 * D2 + 255) / 256, blk, 0, stream>>>(sums, 2 * D2);
        k_colstats<512><<<1024, blk, 0, stream>>>(H1, sums, sumsq);
        k_coeffs<<<2, blk, 0, stream>>>(sums, sumsq, g1 + (size_t)l * D2,
                                        beta1 + (size_t)l * D2, ca, cc, D2);

        // HIN = relu(bn(H1)) @ W2[l] + b2[l] + X
        k_gemm<1, 1><<<dim3(DD / 64, mt), blk, 0, stream>>>(
            H1, W2 + (size_t)l * D2 * DD, b2 + (size_t)l * DD,
            X, ca, cc, HIN, MNODES, D2, DD);

        // BN coeffs for HIN (256 cols)
        k_zero<<<(2 * D2 + 255) / 256, blk, 0, stream>>>(sums, 2 * D2);
        k_colstats<256><<<1024, blk, 0, stream>>>(HIN, sums, sumsq);
        k_coeffs<<<1, blk, 0, stream>>>(sums, sumsq, gf + (size_t)l * DD,
                                        betaf + (size_t)l * DD, ca, cc, DD);

        // X = bn(HIN)
        k_apply<256><<<(nelem4 + 255) / 256, blk, 0, stream>>>(HIN, ca, cc, X, nelem4);
    }
}

// Round 3
// 973.046 us; speedup vs baseline: 9.8681x; 2.1058x over previous
//
#include <hip/hip_runtime.h>

#define MNODES 50000
#define M_PAD  50048          // 391 * 128
#define NEDGES 800000
#define DIN    128
#define DD     256
#define D2     512
#define NLAYERS 3
#define BN_EPS 1e-5f

typedef unsigned short ushort_t;
typedef __bf16 v8bf __attribute__((ext_vector_type(8)));
typedef float  v4f  __attribute__((ext_vector_type(4)));

#define GLOBAL_AS __attribute__((address_space(1)))
#define LDS_AS    __attribute__((address_space(3)))

__device__ __forceinline__ float bf2f(ushort_t u) {
    unsigned x = ((unsigned)u) << 16;
    return __uint_as_float(x);
}
__device__ __forceinline__ ushort_t f2bf(float f) {
    unsigned u = __float_as_uint(f);
    u += 0x7FFF + ((u >> 16) & 1);   // RNE
    return (ushort_t)(u >> 16);
}
__device__ __forceinline__ void async16(const ushort_t* g, ushort_t* l) {
    __builtin_amdgcn_global_load_lds((const GLOBAL_AS unsigned int*)g,
                                     (LDS_AS unsigned int*)l, 16, 0, 0);
}

// ---------------- CSR build ----------------
__global__ void k_zero_int(int* p, int n) {
    int i = blockIdx.x * blockDim.x + threadIdx.x;
    if (i < n) p[i] = 0;
}
__global__ void k_zero(float* p, int n) {
    int i = blockIdx.x * blockDim.x + threadIdx.x;
    if (i < n) p[i] = 0.f;
}
__global__ void k_hist(const int* __restrict__ ei, int* __restrict__ deg) {
    int e = blockIdx.x * blockDim.x + threadIdx.x;
    if (e < NEDGES) atomicAdd(&deg[ei[e * 2 + 1]], 1);
}
__global__ __launch_bounds__(1024)
void k_scan(const int* __restrict__ deg, int* __restrict__ rowptr,
            int* __restrict__ cursor, int n) {
    __shared__ int tmp[1024];
    __shared__ int carry;
    int tid = threadIdx.x;
    if (tid == 0) { carry = 0; rowptr[0] = 0; }
    __syncthreads();
    for (int base = 0; base < n; base += 1024) {
        int i = base + tid;
        int v = (i < n) ? deg[i] : 0;
        tmp[tid] = v;
        __syncthreads();
        #pragma unroll
        for (int off = 1; off < 1024; off <<= 1) {
            int t = (tid >= off) ? tmp[tid - off] : 0;
            __syncthreads();
            tmp[tid] += t;
            __syncthreads();
        }
        if (i < n) {
            int incl = tmp[tid] + carry;
            rowptr[i + 1] = incl;
            cursor[i] = incl - v;
        }
        __syncthreads();
        if (tid == 0) carry += tmp[1023];
        __syncthreads();
    }
}
__global__ void k_fill(const int* __restrict__ ei, int* __restrict__ cursor,
                       int* __restrict__ col) {
    int e = blockIdx.x * blockDim.x + threadIdx.x;
    if (e < NEDGES) {
        int pos = atomicAdd(&cursor[ei[e * 2 + 1]], 1);
        col[pos] = ei[e * 2];
    }
}

// ---------------- weight / input prep ----------------
// WT[n*K+k] = bf16(W[k*N+n])
__global__ void k_prep_wt(const float* __restrict__ W, ushort_t* __restrict__ WT,
                          int K, int N) {
    int i = blockIdx.x * blockDim.x + threadIdx.x;
    if (i >= K * N) return;
    int n = i / K, k = i - n * K;
    WT[i] = f2bf(W[(size_t)k * N + n]);
}
// pre [M,128] f32 -> [M_PAD,128] bf16, pad rows zeroed
__global__ void k_prep_a(const float* __restrict__ src, ushort_t* __restrict__ dst) {
    int i = blockIdx.x * blockDim.x + threadIdx.x;
    if (i >= M_PAD * DIN) return;
    int row = i >> 7;
    dst[i] = f2bf(row < MNODES ? src[i] : 0.f);
}
__global__ void k_initcf(float* __restrict__ ca, float* __restrict__ cc) {
    int i = threadIdx.x;   // 256
    ca[i] = 1.f;
    cc[i] = 0.f;
}

// ---------------- gather: out = caf*(x[n] + sum x[src]) + (deg+1)*ccf ----------
__global__ void k_gather(const int* __restrict__ rowptr, const int* __restrict__ col,
                         const ushort_t* __restrict__ x, const float* __restrict__ ca,
                         const float* __restrict__ cc, ushort_t* __restrict__ out) {
    int node = blockIdx.x * 4 + (threadIdx.x >> 6);
    int lane = threadIdx.x & 63;
    if (node >= MNODES) return;
    const ushort4* xp = (const ushort4*)x;   // 64 ushort4 per row
    ushort4 v = xp[(size_t)node * 64 + lane];
    float a0 = bf2f(v.x), a1 = bf2f(v.y), a2 = bf2f(v.z), a3 = bf2f(v.w);
    int s = rowptr[node], e = rowptr[node + 1];
    int i = s;
    for (; i + 3 < e; i += 4) {
        ushort4 u0 = xp[(size_t)col[i]     * 64 + lane];
        ushort4 u1 = xp[(size_t)col[i + 1] * 64 + lane];
        ushort4 u2 = xp[(size_t)col[i + 2] * 64 + lane];
        ushort4 u3 = xp[(size_t)col[i + 3] * 64 + lane];
        a0 += bf2f(u0.x) + bf2f(u1.x) + bf2f(u2.x) + bf2f(u3.x);
        a1 += bf2f(u0.y) + bf2f(u1.y) + bf2f(u2.y) + bf2f(u3.y);
        a2 += bf2f(u0.z) + bf2f(u1.z) + bf2f(u2.z) + bf2f(u3.z);
        a3 += bf2f(u0.w) + bf2f(u1.w) + bf2f(u2.w) + bf2f(u3.w);
    }
    for (; i < e; i++) {
        ushort4 u = xp[(size_t)col[i] * 64 + lane];
        a0 += bf2f(u.x); a1 += bf2f(u.y); a2 += bf2f(u.z); a3 += bf2f(u.w);
    }
    int c = lane * 4;
    float dn = (float)(e - s) + 1.0f;
    ushort4 o;
    o.x = f2bf(ca[c + 0] * a0 + dn * cc[c + 0]);
    o.y = f2bf(ca[c + 1] * a1 + dn * cc[c + 1]);
    o.z = f2bf(ca[c + 2] * a2 + dn * cc[c + 2]);
    o.w = f2bf(ca[c + 3] * a3 + dn * cc[c + 3]);
    ((ushort4*)out)[(size_t)node * 64 + lane] = o;
}

// ---------------- BN coeff computation ----------------
__global__ void k_coeffs(const float* __restrict__ sums, const float* __restrict__ sumsq,
                         const float* __restrict__ g, const float* __restrict__ beta,
                         float* __restrict__ ca, float* __restrict__ cc, int n) {
    int c = blockIdx.x * blockDim.x + threadIdx.x;
    if (c >= n) return;
    float mean = sums[c] * (1.0f / MNODES);
    float var  = sumsq[c] * (1.0f / MNODES) - mean * mean;
    float a    = g[c] * rsqrtf(var + BN_EPS);
    ca[c] = a;
    cc[c] = beta[c] - a * mean;
}

// ---------------- h = relu(ca*h + cc), in place, bf16, 512 cols ----------------
__global__ void k_prerelu(ushort_t* __restrict__ h, const float* __restrict__ ca,
                          const float* __restrict__ cc) {
    int i = blockIdx.x * blockDim.x + threadIdx.x;  // over M*512/4
    if (i >= MNODES * (D2 / 4)) return;
    int c = (i * 4) & (D2 - 1);
    ushort4 v = ((const ushort4*)h)[i];
    ushort4 o;
    o.x = f2bf(fmaxf(ca[c + 0] * bf2f(v.x) + cc[c + 0], 0.f));
    o.y = f2bf(fmaxf(ca[c + 1] * bf2f(v.y) + cc[c + 1], 0.f));
    o.z = f2bf(fmaxf(ca[c + 2] * bf2f(v.z) + cc[c + 2], 0.f));
    o.w = f2bf(fmaxf(ca[c + 3] * bf2f(v.w) + cc[c + 3], 0.f));
    ((ushort4*)h)[i] = o;
}

// ---------------- final: d_out = ca*h + cc (fp32) ----------------
__global__ void k_apply_out(const ushort_t* __restrict__ h, const float* __restrict__ ca,
                            const float* __restrict__ cc, float* __restrict__ out) {
    int i = blockIdx.x * blockDim.x + threadIdx.x;  // over M*256/4
    if (i >= MNODES * 64) return;
    int c = (i & 63) * 4;
    ushort4 v = ((const ushort4*)h)[i];
    float4 o;
    o.x = ca[c + 0] * bf2f(v.x) + cc[c + 0];
    o.y = ca[c + 1] * bf2f(v.y) + cc[c + 1];
    o.z = ca[c + 2] * bf2f(v.z) + cc[c + 2];
    o.w = ca[c + 3] * bf2f(v.w) + cc[c + 3];
    ((float4*)out)[i] = o;
}

// ---------------- bf16 MFMA GEMM, 128x128 tile, BK=64 ----------------
// out[M,N](bf16) = A[M_PAD,K](bf16) @ WT[N,K]^T(bf16) + bias[N](f32)
//   RES: += r_ca[col]*resid[row,col] + r_cc[col]  (resid bf16, may alias out)
//   DO_STATS: atomicAdd column sums/sumsq of the fp32 result into sums/sumsq
template<int DO_STATS, int RES>
__global__ __launch_bounds__(256)
void k_gemm_bf(const ushort_t* __restrict__ A, const ushort_t* __restrict__ WT,
               const float* __restrict__ bias,
               const ushort_t* resid, const float* __restrict__ r_ca,
               const float* __restrict__ r_cc,
               ushort_t* out, float* __restrict__ sums, float* __restrict__ sumsq,
               int M, int K, int N) {
    __shared__ ushort_t As[128 * 64];   // swizzled: row r chunk c holds global chunk c^(r&7)
    __shared__ ushort_t Bs[128 * 64];
    const int tid = threadIdx.x;
    const int w = tid >> 6, lane = tid & 63;
    const int wm = w >> 1, wn = w & 1;
    const int quad = lane >> 4, l15 = lane & 15;
    const int m0 = blockIdx.y * 128, n0 = blockIdx.x * 128;

    v4f acc[4][4];
    #pragma unroll
    for (int i = 0; i < 4; i++)
        #pragma unroll
        for (int j = 0; j < 4; j++)
            acc[i][j] = (v4f){0.f, 0.f, 0.f, 0.f};

    for (int kt = 0; kt < K; kt += 64) {
        #pragma unroll
        for (int i = 0; i < 4; i++) {        // A tile: 16 wave-issues of 8 rows
            int rblk = i * 4 + w;
            int r = rblk * 8 + (lane >> 3);
            int cg = (lane & 7) ^ (r & 7);
            async16(A + (size_t)(m0 + r) * K + kt + cg * 8, &As[rblk * 512]);
        }
        #pragma unroll
        for (int i = 0; i < 4; i++) {        // B tile from WT rows n0..n0+127
            int rblk = i * 4 + w;
            int r = rblk * 8 + (lane >> 3);
            int cg = (lane & 7) ^ (r & 7);
            async16(WT + (size_t)(n0 + r) * K + kt + cg * 8, &Bs[rblk * 512]);
        }
        __syncthreads();
        #pragma unroll
        for (int ks = 0; ks < 2; ks++) {
            v8bf af[4], bfr[4];
            int cl = (ks * 4 + quad) ^ (l15 & 7);
            #pragma unroll
            for (int t = 0; t < 4; t++) {
                int m_l = wm * 64 + t * 16 + l15;
                af[t] = *(const v8bf*)&As[m_l * 64 + cl * 8];
                int n_l = wn * 64 + t * 16 + l15;
                bfr[t] = *(const v8bf*)&Bs[n_l * 64 + cl * 8];
            }
            #pragma unroll
            for (int mt = 0; mt < 4; mt++)
                #pragma unroll
                for (int nt = 0; nt < 4; nt++)
                    acc[mt][nt] = __builtin_amdgcn_mfma_f32_16x16x32_bf16(
                        af[mt], bfr[nt], acc[mt][nt], 0, 0, 0);
        }
        __syncthreads();
    }

    // epilogue: bias (+ lazy-BN residual) -> bf16 store + fused column stats
    const int mlim = M - m0;
    float s_sum[4] = {0.f, 0.f, 0.f, 0.f}, s_sq[4] = {0.f, 0.f, 0.f, 0.f};
    #pragma unroll
    for (int nt = 0; nt < 4; nt++) {
        int colg = n0 + wn * 64 + nt * 16 + l15;
        float bia = bias[colg];
        float rca = 0.f, rcc = 0.f;
        if (RES) { rca = r_ca[colg]; rcc = r_cc[colg]; }
        #pragma unroll
        for (int mt = 0; mt < 4; mt++) {
            int rbase = wm * 64 + mt * 16 + quad * 4;
            #pragma unroll
            for (int r = 0; r < 4; r++) {
                int rl = rbase + r;
                if (rl < mlim) {
                    size_t idx = (size_t)(m0 + rl) * N + colg;
                    float v = acc[mt][nt][r] + bia;
                    if (RES) v += rca * bf2f(resid[idx]) + rcc;
                    out[idx] = f2bf(v);
                    if (DO_STATS) { s_sum[nt] += v; s_sq[nt] += v * v; }
                }
            }
        }
    }
    if (DO_STATS) {
        #pragma unroll
        for (int nt = 0; nt < 4; nt++) {
            float s = s_sum[nt], q = s_sq[nt];
            s += __shfl_xor(s, 16); q += __shfl_xor(q, 16);
            s += __shfl_xor(s, 32); q += __shfl_xor(q, 32);
            if (quad == 0) {
                int colg = n0 + wn * 64 + nt * 16 + l15;
                atomicAdd(&sums[colg], s);
                atomicAdd(&sumsq[colg], q);
            }
        }
    }
}

extern "C" void kernel_launch(void* const* d_in, const int* in_sizes, int n_in,
                              void* d_out, int out_size, void* d_ws, size_t ws_size,
                              hipStream_t stream) {
    const float* pre   = (const float*)d_in[0];
    const int*   ei    = (const int*)d_in[1];
    const float* W0    = (const float*)d_in[2];
    const float* b0    = (const float*)d_in[3];
    const float* W1    = (const float*)d_in[4];
    const float* b1    = (const float*)d_in[5];
    const float* g1    = (const float*)d_in[6];
    const float* beta1 = (const float*)d_in[7];
    const float* W2    = (const float*)d_in[8];
    const float* b2    = (const float*)d_in[9];
    const float* gf    = (const float*)d_in[10];
    const float* betaf = (const float*)d_in[11];

    char* p = (char*)d_ws;
    ushort_t* preb = (ushort_t*)p; p += (size_t)M_PAD * DIN * 2;
    ushort_t* ACT1 = (ushort_t*)p; p += (size_t)M_PAD * DD * 2;
    ushort_t* ACT2 = (ushort_t*)p; p += (size_t)M_PAD * DD * 2;
    ushort_t* H1   = (ushort_t*)p; p += (size_t)M_PAD * D2 * 2;
    ushort_t* W0T  = (ushort_t*)p; p += (size_t)DIN * DD * 2;
    ushort_t* W1T  = (ushort_t*)p; p += (size_t)NLAYERS * DD * D2 * 2;
    ushort_t* W2T  = (ushort_t*)p; p += (size_t)NLAYERS * D2 * DD * 2;
    float* sums1  = (float*)p; p += D2 * 4;   // sums1+sumsq1 contiguous (zeroed together)
    float* sumsq1 = (float*)p; p += D2 * 4;
    float* ca1    = (float*)p; p += D2 * 4;
    float* cc1    = (float*)p; p += D2 * 4;
    float* sumsF  = (float*)p; p += DD * 4;   // sumsF+sumsqF contiguous
    float* sumsqF = (float*)p; p += DD * 4;
    float* caf    = (float*)p; p += DD * 4;
    float* ccf    = (float*)p; p += DD * 4;
    int* deg    = (int*)p; p += (size_t)MNODES * 4;
    int* rowptr = (int*)p; p += (size_t)(MNODES + 1) * 4;
    int* cursor = (int*)p; p += (size_t)MNODES * 4;
    int* colx   = (int*)p; p += (size_t)NEDGES * 4;

    dim3 blk(256);
    const int mb = (MNODES + 127) / 128;   // 391

    // CSR build
    k_zero_int<<<(MNODES + 255) / 256, blk, 0, stream>>>(deg, MNODES);
    k_hist<<<(NEDGES + 255) / 256, blk, 0, stream>>>(ei, deg);
    k_scan<<<1, 1024, 0, stream>>>(deg, rowptr, cursor, MNODES);
    k_fill<<<(NEDGES + 255) / 256, blk, 0, stream>>>(ei, cursor, colx);

    // weight / input prep (bf16, transposed)
    k_prep_a<<<(M_PAD * DIN + 255) / 256, blk, 0, stream>>>(pre, preb);
    k_prep_wt<<<(DIN * DD + 255) / 256, blk, 0, stream>>>(W0, W0T, DIN, DD);
    for (int l = 0; l < NLAYERS; l++) {
        k_prep_wt<<<(DD * D2 + 255) / 256, blk, 0, stream>>>(
            W1 + (size_t)l * DD * D2, W1T + (size_t)l * DD * D2, DD, D2);
        k_prep_wt<<<(DD * D2 + 255) / 256, blk, 0, stream>>>(
            W2 + (size_t)l * D2 * DD, W2T + (size_t)l * D2 * DD, D2, DD);
    }
    k_initcf<<<1, 256, 0, stream>>>(caf, ccf);

    // X0 = pre @ W0 + b0  -> ACT2 (raw, identity coeffs)
    k_gemm_bf<0, 0><<<dim3(DD / 128, mb), blk, 0, stream>>>(
        preb, W0T, b0, nullptr, nullptr, nullptr, ACT2, nullptr, nullptr,
        MNODES, DIN, DD);

    for (int l = 0; l < NLAYERS; l++) {
        // ACT1 = caf*(ACT2[n] + sum ACT2[src]) + (deg+1)*ccf
        k_gather<<<(MNODES + 3) / 4, blk, 0, stream>>>(rowptr, colx, ACT2, caf, ccf, ACT1);

        // H1 = ACT1 @ W1 + b1, fused column stats
        k_zero<<<(2 * D2 + 255) / 256, blk, 0, stream>>>(sums1, 2 * D2);
        k_gemm_bf<1, 0><<<dim3(D2 / 128, mb), blk, 0, stream>>>(
            ACT1, W1T + (size_t)l * DD * D2, b1 + (size_t)l * D2,
            nullptr, nullptr, nullptr, H1, sums1, sumsq1, MNODES, DD, D2);
        k_coeffs<<<2, blk, 0, stream>>>(sums1, sumsq1, g1 + (size_t)l * D2,
                                        beta1 + (size_t)l * D2, ca1, cc1, D2);

        // H1 = relu(bn1(H1)) in place
        k_prerelu<<<(MNODES * (D2 / 4) + 255) / 256, blk, 0, stream>>>(H1, ca1, cc1);

        // ACT2 = H1 @ W2 + b2 + bn_prev(ACT2)   (in place; fused stats)
        k_zero<<<(2 * DD + 255) / 256, blk, 0, stream>>>(sumsF, 2 * DD);
        k_gemm_bf<1, 1><<<dim3(DD / 128, mb), blk, 0, stream>>>(
            H1, W2T + (size_t)l * D2 * DD, b2 + (size_t)l * DD,
            ACT2, caf, ccf, ACT2, sumsF, sumsqF, MNODES, D2, DD);
        k_coeffs<<<1, blk, 0, stream>>>(sumsF, sumsqF, gf + (size_t)l * DD,
                                        betaf + (size_t)l * DD, caf, ccf, DD);
    }

    // d_out = caf*ACT2 + ccf  (fp32)
    k_apply_out<<<(MNODES * 64 + 255) / 256, blk, 0, stream>>>(ACT2, caf, ccf, (float*)d_out);
}

// Round 4
// 861.823 us; speedup vs baseline: 11.1416x; 1.1291x over previous
//
#include <hip/hip_runtime.h>

#define MNODES 50000
#define M_PAD  50048          // 391 * 128
#define NEDGES 800000
#define DIN    128
#define DD     256
#define D2     512
#define NLAYERS 3
#define BN_EPS 1e-5f

typedef unsigned short ushort_t;
typedef __bf16 v8bf __attribute__((ext_vector_type(8)));
typedef float  v4f  __attribute__((ext_vector_type(4)));

#define GLOBAL_AS __attribute__((address_space(1)))
#define LDS_AS    __attribute__((address_space(3)))

__device__ __forceinline__ float bf2f(ushort_t u) {
    unsigned x = ((unsigned)u) << 16;
    return __uint_as_float(x);
}
__device__ __forceinline__ ushort_t f2bf(float f) {
    unsigned u = __float_as_uint(f);
    u += 0x7FFF + ((u >> 16) & 1);   // RNE
    return (ushort_t)(u >> 16);
}
__device__ __forceinline__ void async16(const ushort_t* g, ushort_t* l) {
    __builtin_amdgcn_global_load_lds((const GLOBAL_AS unsigned int*)g,
                                     (LDS_AS unsigned int*)l, 16, 0, 0);
}

// ---------------- fused prep: bf16 casts, weight transpose, zeroing ----------
// ranges: [0, R0) prep_a | [R0, R1) weight transpose | [R1,+256) caf/ccf init
//         next 1024: zero sums1/sumsq1 | next 512: zero sumsF/sumsqF
//         next MNODES: zero deg
#define R0 (M_PAD * DIN)                       // 6406144
#define RW (DIN * DD + 2 * NLAYERS * DD * D2)  // 819200
__global__ void k_prep_all(const float* __restrict__ pre, ushort_t* __restrict__ preb,
                           const float* __restrict__ W0, const float* __restrict__ W1,
                           const float* __restrict__ W2,
                           ushort_t* __restrict__ W0T, ushort_t* __restrict__ W1T,
                           ushort_t* __restrict__ W2T,
                           float* __restrict__ caf, float* __restrict__ ccf,
                           float* __restrict__ sums1, float* __restrict__ sumsF,
                           int* __restrict__ deg) {
    int i = blockIdx.x * blockDim.x + threadIdx.x;
    if (i < R0) {                       // pre [M,128] f32 -> [M_PAD,128] bf16
        int row = i >> 7;
        preb[i] = f2bf(row < MNODES ? pre[i] : 0.f);
        return;
    }
    int j = i - R0;
    if (j < RW) {                       // WT[n*K+k] = bf16(W[k*N+n])
        if (j < DIN * DD) {
            int n = j >> 7, k = j & 127;
            W0T[j] = f2bf(W0[k * DD + n]);
        } else if (j < DIN * DD + NLAYERS * DD * D2) {
            int j2 = j - DIN * DD;
            int l = j2 >> 17, off = j2 & 131071;
            int n = off >> 8, k = off & 255;      // K=256, N=512
            W1T[(size_t)l * 131072 + off] = f2bf(W1[(size_t)l * 131072 + k * D2 + n]);
        } else {
            int j2 = j - DIN * DD - NLAYERS * DD * D2;
            int l = j2 >> 17, off = j2 & 131071;
            int n = off >> 9, k = off & 511;      // K=512, N=256
            W2T[(size_t)l * 131072 + off] = f2bf(W2[(size_t)l * 131072 + k * DD + n]);
        }
        return;
    }
    j -= RW;
    if (j < 256) { caf[j] = 1.f; ccf[j] = 0.f; return; }
    j -= 256;
    if (j < 1024) { sums1[j] = 0.f; return; }     // sums1+sumsq1 contiguous
    j -= 1024;
    if (j < 512) { sumsF[j] = 0.f; return; }      // sumsF+sumsqF contiguous
    j -= 512;
    if (j < MNODES) deg[j] = 0;
}

// ---------------- CSR build ----------------
__global__ void k_hist(const int* __restrict__ ei, int* __restrict__ deg) {
    int e = blockIdx.x * blockDim.x + threadIdx.x;
    if (e < NEDGES) atomicAdd(&deg[ei[e * 2 + 1]], 1);
}
// phase 1: per-block inclusive scan of 256, store to rowptr[i+1], block total
__global__ void k_scan1(const int* __restrict__ deg, int* __restrict__ rowptr,
                        int* __restrict__ bsum, int n) {
    __shared__ int tmp[256];
    int tid = threadIdx.x;
    int i = blockIdx.x * 256 + tid;
    int v = (i < n) ? deg[i] : 0;
    tmp[tid] = v;
    __syncthreads();
    #pragma unroll
    for (int off = 1; off < 256; off <<= 1) {
        int t = (tid >= off) ? tmp[tid - off] : 0;
        __syncthreads();
        tmp[tid] += t;
        __syncthreads();
    }
    if (i < n) rowptr[i + 1] = tmp[tid];
    if (tid == 255) bsum[blockIdx.x] = tmp[255];
}
// phase 2: single block exclusive-scans the <=256 block sums in place
__global__ __launch_bounds__(256)
void k_scan2(int* __restrict__ bsum, int nb) {
    __shared__ int tmp[256];
    int tid = threadIdx.x;
    int v = (tid < nb) ? bsum[tid] : 0;
    tmp[tid] = v;
    __syncthreads();
    #pragma unroll
    for (int off = 1; off < 256; off <<= 1) {
        int t = (tid >= off) ? tmp[tid - off] : 0;
        __syncthreads();
        tmp[tid] += t;
        __syncthreads();
    }
    if (tid < nb) bsum[tid] = tmp[tid] - v;
}
// phase 3: add block offsets, produce rowptr and cursor
__global__ void k_scan3(const int* __restrict__ deg, const int* __restrict__ bsum,
                        int* __restrict__ rowptr, int* __restrict__ cursor, int n) {
    int i = blockIdx.x * 256 + threadIdx.x;
    if (i == 0) rowptr[0] = 0;
    if (i < n) {
        int incl = rowptr[i + 1] + bsum[i >> 8];
        rowptr[i + 1] = incl;
        cursor[i] = incl - deg[i];
    }
}
__global__ void k_fill(const int* __restrict__ ei, int* __restrict__ cursor,
                       int* __restrict__ col) {
    int e = blockIdx.x * blockDim.x + threadIdx.x;
    if (e < NEDGES) {
        int pos = atomicAdd(&cursor[ei[e * 2 + 1]], 1);
        col[pos] = ei[e * 2];
    }
}

// ---------------- gather: out = caf*(x[n] + sum x[src]) + (deg+1)*ccf ----------
__global__ void k_gather(const int* __restrict__ rowptr, const int* __restrict__ col,
                         const ushort_t* __restrict__ x, const float* __restrict__ ca,
                         const float* __restrict__ cc, ushort_t* __restrict__ out) {
    int node = blockIdx.x * 4 + (threadIdx.x >> 6);
    int lane = threadIdx.x & 63;
    if (node >= MNODES) return;
    const ushort4* xp = (const ushort4*)x;   // 64 ushort4 per row
    ushort4 v = xp[(size_t)node * 64 + lane];
    float a0 = bf2f(v.x), a1 = bf2f(v.y), a2 = bf2f(v.z), a3 = bf2f(v.w);
    int s = rowptr[node], e = rowptr[node + 1];
    int i = s;
    for (; i + 3 < e; i += 4) {
        ushort4 u0 = xp[(size_t)col[i]     * 64 + lane];
        ushort4 u1 = xp[(size_t)col[i + 1] * 64 + lane];
        ushort4 u2 = xp[(size_t)col[i + 2] * 64 + lane];
        ushort4 u3 = xp[(size_t)col[i + 3] * 64 + lane];
        a0 += bf2f(u0.x) + bf2f(u1.x) + bf2f(u2.x) + bf2f(u3.x);
        a1 += bf2f(u0.y) + bf2f(u1.y) + bf2f(u2.y) + bf2f(u3.y);
        a2 += bf2f(u0.z) + bf2f(u1.z) + bf2f(u2.z) + bf2f(u3.z);
        a3 += bf2f(u0.w) + bf2f(u1.w) + bf2f(u2.w) + bf2f(u3.w);
    }
    for (; i < e; i++) {
        ushort4 u = xp[(size_t)col[i] * 64 + lane];
        a0 += bf2f(u.x); a1 += bf2f(u.y); a2 += bf2f(u.z); a3 += bf2f(u.w);
    }
    int c = lane * 4;
    float dn = (float)(e - s) + 1.0f;
    ushort4 o;
    o.x = f2bf(ca[c + 0] * a0 + dn * cc[c + 0]);
    o.y = f2bf(ca[c + 1] * a1 + dn * cc[c + 1]);
    o.z = f2bf(ca[c + 2] * a2 + dn * cc[c + 2]);
    o.w = f2bf(ca[c + 3] * a3 + dn * cc[c + 3]);
    ((ushort4*)out)[(size_t)node * 64 + lane] = o;
}

// ---------------- BN coeff computation (re-zeros stats for next use) ---------
__global__ void k_coeffs(float* __restrict__ sums, float* __restrict__ sumsq,
                         const float* __restrict__ g, const float* __restrict__ beta,
                         float* __restrict__ ca, float* __restrict__ cc, int n) {
    int c = blockIdx.x * blockDim.x + threadIdx.x;
    if (c >= n) return;
    float mean = sums[c] * (1.0f / MNODES);
    float var  = sumsq[c] * (1.0f / MNODES) - mean * mean;
    float a    = g[c] * rsqrtf(var + BN_EPS);
    ca[c] = a;
    cc[c] = beta[c] - a * mean;
    sums[c] = 0.f;
    sumsq[c] = 0.f;
}

// ---------------- h = relu(ca*h + cc), in place, bf16, 512 cols ----------------
__global__ void k_prerelu(ushort_t* __restrict__ h, const float* __restrict__ ca,
                          const float* __restrict__ cc) {
    int i = blockIdx.x * blockDim.x + threadIdx.x;  // over M*512/4
    if (i >= MNODES * (D2 / 4)) return;
    int c = (i * 4) & (D2 - 1);
    ushort4 v = ((const ushort4*)h)[i];
    ushort4 o;
    o.x = f2bf(fmaxf(ca[c + 0] * bf2f(v.x) + cc[c + 0], 0.f));
    o.y = f2bf(fmaxf(ca[c + 1] * bf2f(v.y) + cc[c + 1], 0.f));
    o.z = f2bf(fmaxf(ca[c + 2] * bf2f(v.z) + cc[c + 2], 0.f));
    o.w = f2bf(fmaxf(ca[c + 3] * bf2f(v.w) + cc[c + 3], 0.f));
    ((ushort4*)h)[i] = o;
}

// ---------------- final: d_out = ca*h + cc (fp32) ----------------
__global__ void k_apply_out(const ushort_t* __restrict__ h, const float* __restrict__ ca,
                            const float* __restrict__ cc, float* __restrict__ out) {
    int i = blockIdx.x * blockDim.x + threadIdx.x;  // over M*256/4
    if (i >= MNODES * 64) return;
    int c = (i & 63) * 4;
    ushort4 v = ((const ushort4*)h)[i];
    float4 o;
    o.x = ca[c + 0] * bf2f(v.x) + cc[c + 0];
    o.y = ca[c + 1] * bf2f(v.y) + cc[c + 1];
    o.z = ca[c + 2] * bf2f(v.z) + cc[c + 2];
    o.w = ca[c + 3] * bf2f(v.w) + cc[c + 3];
    ((float4*)out)[i] = o;
}

// ---------------- bf16 MFMA GEMM, 128x128 tile, BK=64 ----------------
template<int DO_STATS, int RES>
__global__ __launch_bounds__(256)
void k_gemm_bf(const ushort_t* __restrict__ A, const ushort_t* __restrict__ WT,
               const float* __restrict__ bias,
               const ushort_t* resid, const float* __restrict__ r_ca,
               const float* __restrict__ r_cc,
               ushort_t* out, float* __restrict__ sums, float* __restrict__ sumsq,
               int M, int K, int N) {
    __shared__ ushort_t As[128 * 64];   // swizzled: row r chunk c holds global chunk c^(r&7)
    __shared__ ushort_t Bs[128 * 64];
    const int tid = threadIdx.x;
    const int w = tid >> 6, lane = tid & 63;
    const int wm = w >> 1, wn = w & 1;
    const int quad = lane >> 4, l15 = lane & 15;
    const int m0 = blockIdx.y * 128, n0 = blockIdx.x * 128;

    v4f acc[4][4];
    #pragma unroll
    for (int i = 0; i < 4; i++)
        #pragma unroll
        for (int j = 0; j < 4; j++)
            acc[i][j] = (v4f){0.f, 0.f, 0.f, 0.f};

    for (int kt = 0; kt < K; kt += 64) {
        #pragma unroll
        for (int i = 0; i < 4; i++) {
            int rblk = i * 4 + w;
            int r = rblk * 8 + (lane >> 3);
            int cg = (lane & 7) ^ (r & 7);
            async16(A + (size_t)(m0 + r) * K + kt + cg * 8, &As[rblk * 512]);
        }
        #pragma unroll
        for (int i = 0; i < 4; i++) {
            int rblk = i * 4 + w;
            int r = rblk * 8 + (lane >> 3);
            int cg = (lane & 7) ^ (r & 7);
            async16(WT + (size_t)(n0 + r) * K + kt + cg * 8, &Bs[rblk * 512]);
        }
        __syncthreads();
        #pragma unroll
        for (int ks = 0; ks < 2; ks++) {
            v8bf af[4], bfr[4];
            int cl = (ks * 4 + quad) ^ (l15 & 7);
            #pragma unroll
            for (int t = 0; t < 4; t++) {
                int m_l = wm * 64 + t * 16 + l15;
                af[t] = *(const v8bf*)&As[m_l * 64 + cl * 8];
                int n_l = wn * 64 + t * 16 + l15;
                bfr[t] = *(const v8bf*)&Bs[n_l * 64 + cl * 8];
            }
            #pragma unroll
            for (int mt = 0; mt < 4; mt++)
                #pragma unroll
                for (int nt = 0; nt < 4; nt++)
                    acc[mt][nt] = __builtin_amdgcn_mfma_f32_16x16x32_bf16(
                        af[mt], bfr[nt], acc[mt][nt], 0, 0, 0);
        }
        __syncthreads();
    }

    const int mlim = M - m0;
    float s_sum[4] = {0.f, 0.f, 0.f, 0.f}, s_sq[4] = {0.f, 0.f, 0.f, 0.f};
    #pragma unroll
    for (int nt = 0; nt < 4; nt++) {
        int colg = n0 + wn * 64 + nt * 16 + l15;
        float bia = bias[colg];
        float rca = 0.f, rcc = 0.f;
        if (RES) { rca = r_ca[colg]; rcc = r_cc[colg]; }
        #pragma unroll
        for (int mt = 0; mt < 4; mt++) {
            int rbase = wm * 64 + mt * 16 + quad * 4;
            #pragma unroll
            for (int r = 0; r < 4; r++) {
                int rl = rbase + r;
                if (rl < mlim) {
                    size_t idx = (size_t)(m0 + rl) * N + colg;
                    float v = acc[mt][nt][r] + bia;
                    if (RES) v += rca * bf2f(resid[idx]) + rcc;
                    out[idx] = f2bf(v);
                    if (DO_STATS) { s_sum[nt] += v; s_sq[nt] += v * v; }
                }
            }
        }
    }
    if (DO_STATS) {
        #pragma unroll
        for (int nt = 0; nt < 4; nt++) {
            float s = s_sum[nt], q = s_sq[nt];
            s += __shfl_xor(s, 16); q += __shfl_xor(q, 16);
            s += __shfl_xor(s, 32); q += __shfl_xor(q, 32);
            if (quad == 0) {
                int colg = n0 + wn * 64 + nt * 16 + l15;
                atomicAdd(&sums[colg], s);
                atomicAdd(&sumsq[colg], q);
            }
        }
    }
}

extern "C" void kernel_launch(void* const* d_in, const int* in_sizes, int n_in,
                              void* d_out, int out_size, void* d_ws, size_t ws_size,
                              hipStream_t stream) {
    const float* pre   = (const float*)d_in[0];
    const int*   ei    = (const int*)d_in[1];
    const float* W0    = (const float*)d_in[2];
    const float* b0    = (const float*)d_in[3];
    const float* W1    = (const float*)d_in[4];
    const float* b1    = (const float*)d_in[5];
    const float* g1    = (const float*)d_in[6];
    const float* beta1 = (const float*)d_in[7];
    const float* W2    = (const float*)d_in[8];
    const float* b2    = (const float*)d_in[9];
    const float* gf    = (const float*)d_in[10];
    const float* betaf = (const float*)d_in[11];

    char* p = (char*)d_ws;
    ushort_t* preb = (ushort_t*)p; p += (size_t)M_PAD * DIN * 2;
    ushort_t* ACT1 = (ushort_t*)p; p += (size_t)M_PAD * DD * 2;
    ushort_t* ACT2 = (ushort_t*)p; p += (size_t)M_PAD * DD * 2;
    ushort_t* H1   = (ushort_t*)p; p += (size_t)M_PAD * D2 * 2;
    ushort_t* W0T  = (ushort_t*)p; p += (size_t)DIN * DD * 2;
    ushort_t* W1T  = (ushort_t*)p; p += (size_t)NLAYERS * DD * D2 * 2;
    ushort_t* W2T  = (ushort_t*)p; p += (size_t)NLAYERS * D2 * DD * 2;
    float* sums1  = (float*)p; p += D2 * 4;   // sums1+sumsq1 contiguous
    float* sumsq1 = (float*)p; p += D2 * 4;
    float* ca1    = (float*)p; p += D2 * 4;
    float* cc1    = (float*)p; p += D2 * 4;
    float* sumsF  = (float*)p; p += DD * 4;   // sumsF+sumsqF contiguous
    float* sumsqF = (float*)p; p += DD * 4;
    float* caf    = (float*)p; p += DD * 4;
    float* ccf    = (float*)p; p += DD * 4;
    int* deg    = (int*)p; p += (size_t)MNODES * 4;
    int* rowptr = (int*)p; p += (size_t)(MNODES + 1) * 4;
    int* cursor = (int*)p; p += (size_t)MNODES * 4;
    int* colx   = (int*)p; p += (size_t)NEDGES * 4;
    int* bsum   = (int*)p; p += 256 * 4;

    dim3 blk(256);
    const int mb = (MNODES + 127) / 128;        // 391
    const int nsb = (MNODES + 255) / 256;       // 196 scan blocks

    // fused prep: bf16 casts, weight transpose, zero deg/stats, init caf/ccf
    const int prep_total = R0 + RW + 256 + 1024 + 512 + MNODES;
    k_prep_all<<<(prep_total + 255) / 256, blk, 0, stream>>>(
        pre, preb, W0, W1, W2, W0T, W1T, W2T, caf, ccf, sums1, sumsF, deg);

    // CSR build
    k_hist<<<(NEDGES + 255) / 256, blk, 0, stream>>>(ei, deg);
    k_scan1<<<nsb, blk, 0, stream>>>(deg, rowptr, bsum, MNODES);
    k_scan2<<<1, blk, 0, stream>>>(bsum, nsb);
    k_scan3<<<nsb, blk, 0, stream>>>(deg, bsum, rowptr, cursor, MNODES);
    k_fill<<<(NEDGES + 255) / 256, blk, 0, stream>>>(ei, cursor, colx);

    // X0 = pre @ W0 + b0  -> ACT2
    k_gemm_bf<0, 0><<<dim3(DD / 128, mb), blk, 0, stream>>>(
        preb, W0T, b0, nullptr, nullptr, nullptr, ACT2, nullptr, nullptr,
        MNODES, DIN, DD);

    for (int l = 0; l < NLAYERS; l++) {
        // ACT1 = caf*(ACT2[n] + sum ACT2[src]) + (deg+1)*ccf
        k_gather<<<(MNODES + 3) / 4, blk, 0, stream>>>(rowptr, colx, ACT2, caf, ccf, ACT1);

        // H1 = ACT1 @ W1 + b1, fused column stats
        k_gemm_bf<1, 0><<<dim3(D2 / 128, mb), blk, 0, stream>>>(
            ACT1, W1T + (size_t)l * DD * D2, b1 + (size_t)l * D2,
            nullptr, nullptr, nullptr, H1, sums1, sumsq1, MNODES, DD, D2);
        k_coeffs<<<2, blk, 0, stream>>>(sums1, sumsq1, g1 + (size_t)l * D2,
                                        beta1 + (size_t)l * D2, ca1, cc1, D2);

        // H1 = relu(bn1(H1)) in place
        k_prerelu<<<(MNODES * (D2 / 4) + 255) / 256, blk, 0, stream>>>(H1, ca1, cc1);

        // ACT2 = H1 @ W2 + b2 + bn_prev(ACT2)  (in place; fused stats)
        k_gemm_bf<1, 1><<<dim3(DD / 128, mb), blk, 0, stream>>>(
            H1, W2T + (size_t)l * D2 * DD, b2 + (size_t)l * DD,
            ACT2, caf, ccf, ACT2, sumsF, sumsqF, MNODES, D2, DD);
        k_coeffs<<<1, blk, 0, stream>>>(sumsF, sumsqF, gf + (size_t)l * DD,
                                        betaf + (size_t)l * DD, caf, ccf, DD);
    }

    // d_out = caf*ACT2 + ccf  (fp32)
    k_apply_out<<<(MNODES * 64 + 255) / 256, blk, 0, stream>>>(ACT2, caf, ccf, (float*)d_out);
}